// Round 8
// baseline (125.559 us; speedup 1.0000x reference)
//
#include <hip/hip_runtime.h>

// YOLO v1 loss — fused float4/NT staging version (R7, resubmitted after
// infra timeout; never benched).
// Shapes: output/target (8192,7,7,30) f32, grid_mask_obj (8192,7,7) i32.
//
// Per 192-thread block = 128 cells = 960 float4 per tensor (exactly 5 per
// thread). 10 x 16B nontemporal loads per thread, all issued up-front into
// static register arrays (half the vmem instructions of R4's 20 x 8B).
// Masks read from global during consume (L1-hot broadcast) -> only ONE
// __syncthreads in the kernel. Consume scatters box/conf channels (ch<10)
// to LDS (stride 11, gcd(11,32)=1) and folds the obj-masked cls SSE
// in-register. Crossing float4s (ch=28) land on chv=0,1 -> always LDS,
// never need the neighbor cell's mask. Per-cell math verified-exact since R2.

typedef float f32x4 __attribute__((ext_vector_type(4)));

constexpr float CELLW_  = 1.0f / 7.0f;
constexpr float IMG_    = 448.0f;
constexpr float INV_BS_ = 1.0f / 8192.0f;
constexpr int   NCELL_  = 8192 * 7 * 7;   // 401408
constexpr int   CPB_    = 128;            // cells per block
constexpr int   TPB_    = 192;            // threads per block (3 waves)
constexpr int   NBLK_   = NCELL_ / CPB_;  // 3136
constexpr int   F4PT_   = 5;              // 960 float4 / 192 threads

__global__ __launch_bounds__(TPB_, 4) void yolo_partial_kernel(
    const float* __restrict__ outp, const float* __restrict__ tgtp,
    const int* __restrict__ maskp, float* __restrict__ partial)
{
    __shared__ float lo[CPB_ * 11];
    __shared__ float lt[CPB_ * 11];

    const int tid   = threadIdx.x;          // 0..191
    const int cell0 = blockIdx.x * CPB_;

    const f32x4* po4 = reinterpret_cast<const f32x4*>(outp) + (size_t)blockIdx.x * 960;
    const f32x4* pt4 = reinterpret_cast<const f32x4*>(tgtp) + (size_t)blockIdx.x * 960;

    // ---- load phase: 10 independent 16B NT loads, all in flight ----
    f32x4 vo[F4PT_], vt[F4PT_];
#pragma unroll
    for (int k = 0; k < F4PT_; ++k) vo[k] = __builtin_nontemporal_load(po4 + tid + TPB_ * k);
#pragma unroll
    for (int k = 0; k < F4PT_; ++k) vt[k] = __builtin_nontemporal_load(pt4 + tid + TPB_ * k);

    float acc = 0.0f;

    // ---- consume: scatter box/conf to LDS, fold cls SSE ----
    // dword d = 4*tid + 768*k; step 768 = 25 cells + 18 channels (even ch kept).
    // float4 covers ch..ch+3; crossing only at ch=28, landing on chv=0,1 (box).
    int c  = (4 * tid) / 30;
    int ch = 4 * tid - 30 * c;

#pragma unroll
    for (int k = 0; k < F4PT_; ++k) {
        const float mf = maskp[cell0 + c] ? 1.0f : 0.0f;   // L1-hot broadcast
        const f32x4 o4 = vo[k];
        const f32x4 t4 = vt[k];
#pragma unroll
        for (int j = 0; j < 4; ++j) {
            const int  chj   = ch + j;
            const bool cross = (chj >= 30);
            const int  cv    = cross ? c + 1 : c;
            const int  chv   = cross ? chj - 30 : chj;
            const float ov = (j == 0) ? o4.x : (j == 1) ? o4.y : (j == 2) ? o4.z : o4.w;
            const float tv = (j == 0) ? t4.x : (j == 1) ? t4.y : (j == 2) ? t4.z : t4.w;
            if (chv < 10) {
                lo[cv * 11 + chv] = ov;
                lt[cv * 11 + chv] = tv;
            } else {
                const float d = ov - tv;
                acc += mf * d * d;
            }
        }
        ch += 18; c += 25;
        if (ch >= 30) { ch -= 30; c += 1; }
    }
    __syncthreads();                        // the only barrier before reduce

    // ---- per-cell box math (threads 0..127 own one cell each) ----
    if (tid < CPB_) {
        const float* o = &lo[tid * 11];
        const float* t = &lt[tid * 11];
        const int    m = maskp[cell0 + tid];   // L1-hot

        const int rem = (cell0 + tid) % 49;    // row = rem/7 (y), col = rem%7 (x)
        const float gx = (float)(rem % 7) * CELLW_;
        const float gy = (float)(rem / 7) * CELLW_;

        // target box 0 -> pixel corners
        const float tx = (t[0] * CELLW_ + gx) * IMG_;
        const float ty = (t[1] * CELLW_ + gy) * IMG_;
        const float tw = t[2] * IMG_, th = t[3] * IMG_;
        const float tx1 = tx - tw * 0.5f, tx2 = tx + tw * 0.5f;
        const float ty1 = ty - th * 0.5f, ty2 = ty + th * 0.5f;
        const float area_t = (tx2 - tx1) * (ty2 - ty1);

        float iou[2];
#pragma unroll
        for (int b = 0; b < 2; ++b) {
            float b0 = (b == 0) ? o[0] : o[5];
            float b1 = (b == 0) ? o[1] : o[6];
            float b2 = (b == 0) ? o[2] : o[7];
            float b3 = (b == 0) ? o[3] : o[8];
            float x = (b0 * CELLW_ + gx) * IMG_;
            float y = (b1 * CELLW_ + gy) * IMG_;
            float w = b2 * IMG_, h = b3 * IMG_;
            float x1 = x - w * 0.5f, x2 = x + w * 0.5f;
            float y1 = y - h * 0.5f, y2 = y + h * 0.5f;
            float iw = fmaxf(fminf(x2, tx2) - fmaxf(x1, tx1), 0.0f);
            float ih = fmaxf(fminf(y2, ty2) - fmaxf(y1, ty1), 0.0f);
            float inter = iw * ih;
            float area_o = (x2 - x1) * (y2 - y1);
            iou[b] = inter / (area_o + area_t - inter);
        }

        const int   max_id  = (iou[1] > iou[0]) ? 1 : 0;   // argmax, tie->first
        const float max_iou = fmaxf(iou[0], iou[1]);

        // selected box (static indices via ternaries — no runtime indexing)
        const float so0 = max_id ? o[5] : o[0];
        const float so1 = max_id ? o[6] : o[1];
        const float so2 = max_id ? o[7] : o[2];
        const float so3 = max_id ? o[8] : o[3];
        const float st0 = max_id ? t[5] : t[0];
        const float st1 = max_id ? t[6] : t[1];
        const float st2 = max_id ? t[7] : t[2];
        const float st3 = max_id ? t[8] : t[3];

        const float dxy0 = so0 - st0, dxy1 = so1 - st1;
        const float xy_loss = dxy0 * dxy0 + dxy1 * dxy1;

        const float dwh0 = sqrtf(so2) - sqrtf(st2);
        const float dwh1 = sqrtf(so3) - sqrtf(st3);
        const float wh_loss = dwh0 * dwh0 + dwh1 * dwh1;

        // conf-obj term: id_conf degenerates to 0 when max_iou == 0
        const int   id_conf = (max_iou > 0.0f) ? max_id : 0;
        const float sel_c   = id_conf ? o[9] : o[4];
        const float sel_iou = (id_conf == max_id) ? max_iou : 0.0f;
        const float dcf     = sel_c - sel_iou;
        const float c_obj   = dcf * dcf;

        // noobj conf term (both boxes)
        const float dn0 = o[4] - t[4], dn1 = o[9] - t[9];
        const float c_noobj = dn0 * dn0 + dn1 * dn1;

        acc += m ? (5.0f * (xy_loss + wh_loss) + c_obj)
                 : (0.5f * c_noobj);
        // (cls term already accumulated during staging, obj-masked)
    }

    // ---- wave (64-lane) + block reduction, plain store ----
#pragma unroll
    for (int off = 32; off > 0; off >>= 1)
        acc += __shfl_down(acc, off);

    __shared__ float wsum[3];
    const int lane = threadIdx.x & 63;
    const int wid  = threadIdx.x >> 6;
    if (lane == 0) wsum[wid] = acc;
    __syncthreads();
    if (threadIdx.x == 0)
        partial[blockIdx.x] = wsum[0] + wsum[1] + wsum[2];
}

__global__ __launch_bounds__(256) void yolo_reduce_kernel(
    const float* __restrict__ partial, float* __restrict__ out)
{
    float a = 0.0f;
    for (int i = threadIdx.x; i < NBLK_; i += 256)
        a += partial[i];

#pragma unroll
    for (int off = 32; off > 0; off >>= 1)
        a += __shfl_down(a, off);

    __shared__ float wsum[4];
    const int lane = threadIdx.x & 63;
    const int wid  = threadIdx.x >> 6;
    if (lane == 0) wsum[wid] = a;
    __syncthreads();
    if (threadIdx.x == 0)
        out[0] = (wsum[0] + wsum[1] + wsum[2] + wsum[3]) * INV_BS_;
}

extern "C" void kernel_launch(void* const* d_in, const int* in_sizes, int n_in,
                              void* d_out, int out_size, void* d_ws, size_t ws_size,
                              hipStream_t stream) {
    const float* outp = (const float*)d_in[0];
    const float* tgtp = (const float*)d_in[1];
    const int*   mask = (const int*)d_in[2];
    float*       res  = (float*)d_out;
    float*       part = (float*)d_ws;     // 3136 floats of scratch

    yolo_partial_kernel<<<NBLK_, TPB_, 0, stream>>>(outp, tgtp, mask, part);
    yolo_reduce_kernel<<<1, 256, 0, stream>>>(part, res);
}